// Round 9
// baseline (502.926 us; speedup 1.0000x reference)
//
#include <hip/hip_runtime.h>
#include <math.h>

#define NN 50000
#define D 128
#define BM 64   // rows per block in sage_layer
#define NB 49   // scan blocks: ceil(50000/1024)

// ---- CSR build ----------------------------------------------------------

__global__ void count_kernel(const int* __restrict__ e, int E, int* __restrict__ cnt) {
    int i = blockIdx.x * blockDim.x + threadIdx.x;
    if (i < E) atomicAdd(&cnt[e[E + i]], 1);
}

// 49 blocks x 256 threads, 4 elems/thread: block-local exclusive scan
__global__ __launch_bounds__(256) void scan_blocks_kernel(const int* __restrict__ cnt,
                                                          int* __restrict__ row_ptr,
                                                          int* __restrict__ bsum, int N) {
    __shared__ int wsum[4], woff[4];
    int t = threadIdx.x;
    int lane = t & 63, wave = t >> 6;
    int base = blockIdx.x * 1024 + t * 4;
    int4 v = make_int4(0, 0, 0, 0);
    if (base + 4 <= N) v = *(const int4*)(cnt + base);
    int s = v.x + v.y + v.z + v.w;
    int incl = s;
    for (int off = 1; off < 64; off <<= 1) {
        int u = __shfl_up(incl, off);
        if (lane >= off) incl += u;
    }
    if (lane == 63) wsum[wave] = incl;
    __syncthreads();
    if (t == 0) {
        int r = 0;
        #pragma unroll
        for (int w = 0; w < 4; ++w) { woff[w] = r; r += wsum[w]; }
    }
    __syncthreads();
    int excl = woff[wave] + incl - s;
    if (base + 4 <= N) {
        int4 rp;
        rp.x = excl;
        rp.y = rp.x + v.x;
        rp.z = rp.y + v.y;
        rp.w = rp.z + v.z;
        *(int4*)(row_ptr + base) = rp;
    }
    if (t == 255) bsum[blockIdx.x] = woff[3] + wsum[3];
}

// single tiny block: exclusive scan of the 49 block sums (in place)
__global__ __launch_bounds__(64) void scan_bsums_kernel(int* __restrict__ bsum, int nb) {
    int l = threadIdx.x;
    int v = (l < nb) ? bsum[l] : 0;
    int incl = v;
    for (int off = 1; off < 64; off <<= 1) {
        int u = __shfl_up(incl, off);
        if (l >= off) incl += u;
    }
    if (l < nb) bsum[l] = incl - v;
}

__global__ __launch_bounds__(256) void scan_add_kernel(const int* __restrict__ cnt,
                                                       int* __restrict__ row_ptr,
                                                       const int* __restrict__ bsum,
                                                       float* __restrict__ inv_cnt,
                                                       int N, int E) {
    int base = blockIdx.x * 1024 + threadIdx.x * 4;
    int off = bsum[blockIdx.x];
    if (base + 4 <= N) {
        int4 rp = *(int4*)(row_ptr + base);
        rp.x += off; rp.y += off; rp.z += off; rp.w += off;
        *(int4*)(row_ptr + base) = rp;
        int4 c = *(const int4*)(cnt + base);
        float4 ic;
        ic.x = 1.0f / fmaxf((float)c.x, 1.0f);
        ic.y = 1.0f / fmaxf((float)c.y, 1.0f);
        ic.z = 1.0f / fmaxf((float)c.z, 1.0f);
        ic.w = 1.0f / fmaxf((float)c.w, 1.0f);
        *(float4*)(inv_cnt + base) = ic;
    }
    if (blockIdx.x == 0 && threadIdx.x == 0) row_ptr[N] = E;
}

__global__ void scatter_kernel(const int* __restrict__ e, int E,
                               const int* __restrict__ row_ptr,
                               int* __restrict__ fill,
                               int* __restrict__ csr_src) {
    int i = blockIdx.x * blockDim.x + threadIdx.x;
    if (i < E) {
        int d = e[E + i];
        int pos = row_ptr[d] + atomicAdd(&fill[d], 1);
        csr_src[pos] = e[i];
    }
}

// ---- mean aggregation: one 32-lane group per node, float4 lanes ---------
// 8-wide edge batches: shfl 8 indices, issue 8 independent gathers, tree
// accumulate into 2 chains -> ~16 outstanding loads per wave.

__global__ __launch_bounds__(256) void aggregate_kernel(const float* __restrict__ h,
                                                        const int* __restrict__ row_ptr,
                                                        const int* __restrict__ csr_src,
                                                        const float* __restrict__ inv_cnt,
                                                        float* __restrict__ agg, int N) {
    int node = (int)((blockIdx.x * blockDim.x + threadIdx.x) >> 5);
    int l = threadIdx.x & 31;
    if (node >= N) return;
    const float4* h4 = (const float4*)h;
    int beg = row_ptr[node], end = row_ptr[node + 1];
    float4 a0 = make_float4(0.f, 0.f, 0.f, 0.f);
    float4 a1 = make_float4(0.f, 0.f, 0.f, 0.f);
    for (int base = beg; base < end; base += 32) {
        int idx = 0;
        if (base + l < end) idx = csr_src[base + l];
        int n = min(32, end - base);
        int j = 0;
        for (; j + 8 <= n; j += 8) {
            int s0 = __shfl(idx, j + 0, 32);
            int s1 = __shfl(idx, j + 1, 32);
            int s2 = __shfl(idx, j + 2, 32);
            int s3 = __shfl(idx, j + 3, 32);
            int s4 = __shfl(idx, j + 4, 32);
            int s5 = __shfl(idx, j + 5, 32);
            int s6 = __shfl(idx, j + 6, 32);
            int s7 = __shfl(idx, j + 7, 32);
            float4 v0 = h4[(size_t)s0 * 32 + l];
            float4 v1 = h4[(size_t)s1 * 32 + l];
            float4 v2 = h4[(size_t)s2 * 32 + l];
            float4 v3 = h4[(size_t)s3 * 32 + l];
            float4 v4 = h4[(size_t)s4 * 32 + l];
            float4 v5 = h4[(size_t)s5 * 32 + l];
            float4 v6 = h4[(size_t)s6 * 32 + l];
            float4 v7 = h4[(size_t)s7 * 32 + l];
            a0.x += v0.x + v2.x; a0.y += v0.y + v2.y; a0.z += v0.z + v2.z; a0.w += v0.w + v2.w;
            a1.x += v1.x + v3.x; a1.y += v1.y + v3.y; a1.z += v1.z + v3.z; a1.w += v1.w + v3.w;
            a0.x += v4.x + v6.x; a0.y += v4.y + v6.y; a0.z += v4.z + v6.z; a0.w += v4.w + v6.w;
            a1.x += v5.x + v7.x; a1.y += v5.y + v7.y; a1.z += v5.z + v7.z; a1.w += v5.w + v7.w;
        }
        for (; j < n; ++j) {
            int s = __shfl(idx, j, 32);
            float4 v = h4[(size_t)s * 32 + l];
            a0.x += v.x; a0.y += v.y; a0.z += v.z; a0.w += v.w;
        }
    }
    float iv = inv_cnt[node];
    ((float4*)agg)[(size_t)node * 32 + l] =
        make_float4((a0.x + a1.x) * iv, (a0.y + a1.y) * iv,
                    (a0.z + a1.z) * iv, (a0.w + a1.w) * iv);
}

// ---- fused dual-GEMM + bias + L2-normalize + (ReLU), register-tiled -----
// K-split staging: inputs staged in LDS 64 k at a time (32 KB total ->
// 4-5 blocks/CU vs 2 with full-K staging). Weights stream from L2 as in
// the round-5 known-good version; inner loop body identical (no extra
// unroll pragmas -- k4-loop unrolling spills to scratch).

__global__ __launch_bounds__(256, 4) void sage_layer_kernel(const float* __restrict__ x,
                                                            const float* __restrict__ agg,
                                                            const float* __restrict__ Wl,
                                                            const float* __restrict__ bl,
                                                            const float* __restrict__ Wr,
                                                            float* __restrict__ out,
                                                            int relu, int N) {
    __shared__ float sA[BM * 64];   // 16 KB (64 rows x 64 k)
    __shared__ float sX[BM * 64];   // 16 KB
    int t = threadIdx.x;
    int row0 = blockIdx.x * BM;
    int ct = t & 31;
    int rt = t >> 5;
    int r0 = rt * 8;

    float acc[8][4];
    {
        float4 b4 = ((const float4*)bl)[ct];
        #pragma unroll
        for (int i = 0; i < 8; ++i) {
            acc[i][0] = b4.x; acc[i][1] = b4.y; acc[i][2] = b4.z; acc[i][3] = b4.w;
        }
    }

    const float4* Wl4 = (const float4*)Wl;
    const float4* Wr4 = (const float4*)Wr;
    const float4* a4g = (const float4*)agg;
    const float4* x4g = (const float4*)x;
    float4* sA4w = (float4*)sA;
    float4* sX4w = (float4*)sX;
    const float4* sA4 = (const float4*)sA;
    const float4* sX4 = (const float4*)sX;

    #pragma unroll 1
    for (int kb = 0; kb < 2; ++kb) {
        int kb16 = kb * 16;           // float4 offset of this K-half
        if (kb) __syncthreads();      // protect LDS before overwrite
        // stage 64 rows x 16 float4 per matrix; 256 threads x 4 each
        #pragma unroll
        for (int i = 0; i < 4; ++i) {
            int idx = t + i * 256;            // 0..1023
            int r = idx >> 4, c = idx & 15;   // row, float4-col within half
            int gr = row0 + r;
            float4 va = make_float4(0.f, 0.f, 0.f, 0.f);
            float4 vx = va;
            if (gr < N) {
                va = a4g[(size_t)gr * 32 + kb16 + c];
                vx = x4g[(size_t)gr * 32 + kb16 + c];
            }
            sA4w[idx] = va;
            sX4w[idx] = vx;
        }
        __syncthreads();

        #pragma unroll 1
        for (int k4 = 0; k4 < 16; ++k4) {
            int kbg = kb * 64 + k4 * 4;       // global k of this step
            float4 wl0 = Wl4[(kbg + 0) * 32 + ct];
            float4 wl1 = Wl4[(kbg + 1) * 32 + ct];
            float4 wl2 = Wl4[(kbg + 2) * 32 + ct];
            float4 wl3 = Wl4[(kbg + 3) * 32 + ct];
            float4 wr0 = Wr4[(kbg + 0) * 32 + ct];
            float4 wr1 = Wr4[(kbg + 1) * 32 + ct];
            float4 wr2 = Wr4[(kbg + 2) * 32 + ct];
            float4 wr3 = Wr4[(kbg + 3) * 32 + ct];
            #pragma unroll
            for (int i = 0; i < 8; ++i) {
                float4 a4 = sA4[(r0 + i) * 16 + k4];
                float4 x4 = sX4[(r0 + i) * 16 + k4];
                acc[i][0] += a4.x * wl0.x + a4.y * wl1.x + a4.z * wl2.x + a4.w * wl3.x
                           + x4.x * wr0.x + x4.y * wr1.x + x4.z * wr2.x + x4.w * wr3.x;
                acc[i][1] += a4.x * wl0.y + a4.y * wl1.y + a4.z * wl2.y + a4.w * wl3.y
                           + x4.x * wr0.y + x4.y * wr1.y + x4.z * wr2.y + x4.w * wr3.y;
                acc[i][2] += a4.x * wl0.z + a4.y * wl1.z + a4.z * wl2.z + a4.w * wl3.z
                           + x4.x * wr0.z + x4.y * wr1.z + x4.z * wr2.z + x4.w * wr3.z;
                acc[i][3] += a4.x * wl0.w + a4.y * wl1.w + a4.z * wl2.w + a4.w * wl3.w
                           + x4.x * wr0.w + x4.y * wr1.w + x4.z * wr2.w + x4.w * wr3.w;
            }
        }
    }

    float4* out4 = (float4*)out;
    #pragma unroll
    for (int i = 0; i < 8; ++i) {
        float s = acc[i][0] * acc[i][0] + acc[i][1] * acc[i][1]
                + acc[i][2] * acc[i][2] + acc[i][3] * acc[i][3];
        for (int off = 16; off; off >>= 1) s += __shfl_xor(s, off);
        float inv = 1.0f / fmaxf(sqrtf(s), 1e-12f);
        float4 o;
        o.x = acc[i][0] * inv; o.y = acc[i][1] * inv;
        o.z = acc[i][2] * inv; o.w = acc[i][3] * inv;
        if (relu) {
            o.x = fmaxf(o.x, 0.f); o.y = fmaxf(o.y, 0.f);
            o.z = fmaxf(o.z, 0.f); o.w = fmaxf(o.w, 0.f);
        }
        int gr = row0 + r0 + i;
        if (gr < N) out4[(size_t)gr * 32 + ct] = o;
    }
}

// ---- final FC + softmax: LDS-tiled, 32 rows/block, 8 threads/row --------

__global__ __launch_bounds__(256, 4) void fc_softmax_kernel(const float* __restrict__ h,
                                                            const float* __restrict__ Wfc,
                                                            const float* __restrict__ bfc,
                                                            float* __restrict__ out, int N) {
    __shared__ float sH[32 * 132];  // 16.9 KB
    __shared__ float sW[128 * 40];  // 20.5 KB
    __shared__ float sB[40];
    int t = threadIdx.x;
    int row0 = blockIdx.x * 32;

    const float4* W4 = (const float4*)Wfc;
    float4* sW4 = (float4*)sW;
    for (int i = t; i < 1280; i += 256) sW4[i] = W4[i];
    if (t < 40) sB[t] = bfc[t];

    const float4* h4 = (const float4*)h;
    for (int i = t; i < 32 * 32; i += 256) {
        int r = i >> 5, c = i & 31;
        int gr = row0 + r;
        float4 v = make_float4(0.f, 0.f, 0.f, 0.f);
        if (gr < N) v = h4[(size_t)gr * 32 + c];
        *(float4*)(sH + r * 132 + c * 4) = v;
    }
    __syncthreads();

    int r = t >> 3, sub = t & 7;
    int c0 = sub * 5;
    float acc[5];
    #pragma unroll
    for (int i = 0; i < 5; ++i) acc[i] = sB[c0 + i];

    const float* hr = sH + r * 132;
    for (int k = 0; k < 128; ++k) {
        float hv = hr[k];
        const float* wk = sW + k * 40 + c0;
        #pragma unroll
        for (int i = 0; i < 5; ++i) acc[i] += hv * wk[i];
    }

    float m = acc[0];
    #pragma unroll
    for (int i = 1; i < 5; ++i) m = fmaxf(m, acc[i]);
    for (int off = 1; off < 8; off <<= 1) m = fmaxf(m, __shfl_xor(m, off));
    float s = 0.f;
    #pragma unroll
    for (int i = 0; i < 5; ++i) { acc[i] = expf(acc[i] - m); s += acc[i]; }
    for (int off = 1; off < 8; off <<= 1) s += __shfl_xor(s, off);
    float inv = 1.0f / s;

    int gr = row0 + r;
    if (gr < N) {
        #pragma unroll
        for (int i = 0; i < 5; ++i) out[(size_t)gr * 40 + c0 + i] = acc[i] * inv;
    }
}

// ---- launcher -----------------------------------------------------------

extern "C" void kernel_launch(void* const* d_in, const int* in_sizes, int n_in,
                              void* d_out, int out_size, void* d_ws, size_t ws_size,
                              hipStream_t stream) {
    const float* x   = (const float*)d_in[0];
    const int*   e   = (const int*)d_in[1];
    const float* W1l = (const float*)d_in[2];
    const float* b1  = (const float*)d_in[3];
    const float* W1r = (const float*)d_in[4];
    const float* W2l = (const float*)d_in[5];
    const float* b2  = (const float*)d_in[6];
    const float* W2r = (const float*)d_in[7];
    const float* W3l = (const float*)d_in[8];
    const float* b3  = (const float*)d_in[9];
    const float* W3r = (const float*)d_in[10];
    const float* Wfc = (const float*)d_in[11];
    const float* bfc = (const float*)d_in[12];
    float* out = (float*)d_out;

    const int N = NN;
    const int E = in_sizes[1] / 2;

    // 16B-aligned sections
    float* h1      = (float*)d_ws;
    float* h2      = h1 + (size_t)N * D;
    float* agg     = h2 + (size_t)N * D;
    float* inv_cnt = agg + (size_t)N * D;          // N floats (N%4==0)
    int*   row_ptr = (int*)(inv_cnt + N);          // N+4 ints
    int*   cnt     = row_ptr + (N + 4);            // N ints
    int*   fill    = cnt + N;                      // N ints
    int*   bsum    = fill + N;                     // 64 ints
    int*   csr_src = bsum + 64;                    // E ints

    hipMemsetAsync(cnt, 0, sizeof(int) * N, stream);
    hipMemsetAsync(fill, 0, sizeof(int) * N, stream);

    count_kernel<<<(E + 255) / 256, 256, 0, stream>>>(e, E, cnt);
    scan_blocks_kernel<<<NB, 256, 0, stream>>>(cnt, row_ptr, bsum, N);
    scan_bsums_kernel<<<1, 64, 0, stream>>>(bsum, NB);
    scan_add_kernel<<<NB, 256, 0, stream>>>(cnt, row_ptr, bsum, inv_cnt, N, E);
    scatter_kernel<<<(E + 255) / 256, 256, 0, stream>>>(e, E, row_ptr, fill, csr_src);

    int aggBlocks = (N * 32 + 255) / 256;
    int sageBlocks = (N + BM - 1) / BM;
    int fcBlocks = (N + 31) / 32;

    aggregate_kernel<<<aggBlocks, 256, 0, stream>>>(x, row_ptr, csr_src, inv_cnt, agg, N);
    sage_layer_kernel<<<sageBlocks, 256, 0, stream>>>(x, agg, W1l, b1, W1r, h1, 1, N);

    aggregate_kernel<<<aggBlocks, 256, 0, stream>>>(h1, row_ptr, csr_src, inv_cnt, agg, N);
    sage_layer_kernel<<<sageBlocks, 256, 0, stream>>>(h1, agg, W2l, b2, W2r, h2, 1, N);

    aggregate_kernel<<<aggBlocks, 256, 0, stream>>>(h2, row_ptr, csr_src, inv_cnt, agg, N);
    sage_layer_kernel<<<sageBlocks, 256, 0, stream>>>(h2, agg, W3l, b3, W3r, h1, 0, N);

    fc_softmax_kernel<<<fcBlocks, 256, 0, stream>>>(h1, Wfc, bfc, out, N);
}

// Round 10
// 475.812 us; speedup vs baseline: 1.0570x; 1.0570x over previous
//
#include <hip/hip_runtime.h>
#include <math.h>

#define NN 50000
#define D 128
#define BM 64   // rows per block in sage_layer
#define NB 49   // scan blocks: ceil(50000/1024)

// ---- CSR build ----------------------------------------------------------

__global__ void count_kernel(const int* __restrict__ e, int E, int* __restrict__ cnt) {
    int i = blockIdx.x * blockDim.x + threadIdx.x;
    if (i < E) atomicAdd(&cnt[e[E + i]], 1);
}

// 49 blocks x 256 threads, 4 elems/thread: block-local exclusive scan
__global__ __launch_bounds__(256) void scan_blocks_kernel(const int* __restrict__ cnt,
                                                          int* __restrict__ row_ptr,
                                                          int* __restrict__ bsum, int N) {
    __shared__ int wsum[4], woff[4];
    int t = threadIdx.x;
    int lane = t & 63, wave = t >> 6;
    int base = blockIdx.x * 1024 + t * 4;
    int4 v = make_int4(0, 0, 0, 0);
    if (base + 4 <= N) v = *(const int4*)(cnt + base);
    int s = v.x + v.y + v.z + v.w;
    int incl = s;
    for (int off = 1; off < 64; off <<= 1) {
        int u = __shfl_up(incl, off);
        if (lane >= off) incl += u;
    }
    if (lane == 63) wsum[wave] = incl;
    __syncthreads();
    if (t == 0) {
        int r = 0;
        #pragma unroll
        for (int w = 0; w < 4; ++w) { woff[w] = r; r += wsum[w]; }
    }
    __syncthreads();
    int excl = woff[wave] + incl - s;
    if (base + 4 <= N) {
        int4 rp;
        rp.x = excl;
        rp.y = rp.x + v.x;
        rp.z = rp.y + v.y;
        rp.w = rp.z + v.z;
        *(int4*)(row_ptr + base) = rp;
    }
    if (t == 255) bsum[blockIdx.x] = woff[3] + wsum[3];
}

// single tiny block: exclusive scan of the 49 block sums (in place)
__global__ __launch_bounds__(64) void scan_bsums_kernel(int* __restrict__ bsum, int nb) {
    int l = threadIdx.x;
    int v = (l < nb) ? bsum[l] : 0;
    int incl = v;
    for (int off = 1; off < 64; off <<= 1) {
        int u = __shfl_up(incl, off);
        if (l >= off) incl += u;
    }
    if (l < nb) bsum[l] = incl - v;
}

__global__ __launch_bounds__(256) void scan_add_kernel(const int* __restrict__ cnt,
                                                       int* __restrict__ row_ptr,
                                                       const int* __restrict__ bsum,
                                                       float* __restrict__ inv_cnt,
                                                       int N, int E) {
    int base = blockIdx.x * 1024 + threadIdx.x * 4;
    int off = bsum[blockIdx.x];
    if (base + 4 <= N) {
        int4 rp = *(int4*)(row_ptr + base);
        rp.x += off; rp.y += off; rp.z += off; rp.w += off;
        *(int4*)(row_ptr + base) = rp;
        int4 c = *(const int4*)(cnt + base);
        float4 ic;
        ic.x = 1.0f / fmaxf((float)c.x, 1.0f);
        ic.y = 1.0f / fmaxf((float)c.y, 1.0f);
        ic.z = 1.0f / fmaxf((float)c.z, 1.0f);
        ic.w = 1.0f / fmaxf((float)c.w, 1.0f);
        *(float4*)(inv_cnt + base) = ic;
    }
    if (blockIdx.x == 0 && threadIdx.x == 0) row_ptr[N] = E;
}

__global__ void scatter_kernel(const int* __restrict__ e, int E,
                               const int* __restrict__ row_ptr,
                               int* __restrict__ fill,
                               int* __restrict__ csr_src) {
    int i = blockIdx.x * blockDim.x + threadIdx.x;
    if (i < E) {
        int d = e[E + i];
        int pos = row_ptr[d] + atomicAdd(&fill[d], 1);
        csr_src[pos] = e[i];
    }
}

// ---- mean aggregation: one 32-lane group per node, float4 lanes ---------
// 8-wide edge batches: shfl 8 indices, issue 8 independent gathers, tree
// accumulate into 2 chains -> ~16 outstanding loads per wave.

__global__ __launch_bounds__(256) void aggregate_kernel(const float* __restrict__ h,
                                                        const int* __restrict__ row_ptr,
                                                        const int* __restrict__ csr_src,
                                                        const float* __restrict__ inv_cnt,
                                                        float* __restrict__ agg, int N) {
    int node = (int)((blockIdx.x * blockDim.x + threadIdx.x) >> 5);
    int l = threadIdx.x & 31;
    if (node >= N) return;
    const float4* h4 = (const float4*)h;
    int beg = row_ptr[node], end = row_ptr[node + 1];
    float4 a0 = make_float4(0.f, 0.f, 0.f, 0.f);
    float4 a1 = make_float4(0.f, 0.f, 0.f, 0.f);
    for (int base = beg; base < end; base += 32) {
        int idx = 0;
        if (base + l < end) idx = csr_src[base + l];
        int n = min(32, end - base);
        int j = 0;
        for (; j + 8 <= n; j += 8) {
            int s0 = __shfl(idx, j + 0, 32);
            int s1 = __shfl(idx, j + 1, 32);
            int s2 = __shfl(idx, j + 2, 32);
            int s3 = __shfl(idx, j + 3, 32);
            int s4 = __shfl(idx, j + 4, 32);
            int s5 = __shfl(idx, j + 5, 32);
            int s6 = __shfl(idx, j + 6, 32);
            int s7 = __shfl(idx, j + 7, 32);
            float4 v0 = h4[(size_t)s0 * 32 + l];
            float4 v1 = h4[(size_t)s1 * 32 + l];
            float4 v2 = h4[(size_t)s2 * 32 + l];
            float4 v3 = h4[(size_t)s3 * 32 + l];
            float4 v4 = h4[(size_t)s4 * 32 + l];
            float4 v5 = h4[(size_t)s5 * 32 + l];
            float4 v6 = h4[(size_t)s6 * 32 + l];
            float4 v7 = h4[(size_t)s7 * 32 + l];
            a0.x += v0.x + v2.x; a0.y += v0.y + v2.y; a0.z += v0.z + v2.z; a0.w += v0.w + v2.w;
            a1.x += v1.x + v3.x; a1.y += v1.y + v3.y; a1.z += v1.z + v3.z; a1.w += v1.w + v3.w;
            a0.x += v4.x + v6.x; a0.y += v4.y + v6.y; a0.z += v4.z + v6.z; a0.w += v4.w + v6.w;
            a1.x += v5.x + v7.x; a1.y += v5.y + v7.y; a1.z += v5.z + v7.z; a1.w += v5.w + v7.w;
        }
        for (; j < n; ++j) {
            int s = __shfl(idx, j, 32);
            float4 v = h4[(size_t)s * 32 + l];
            a0.x += v.x; a0.y += v.y; a0.z += v.z; a0.w += v.w;
        }
    }
    float iv = inv_cnt[node];
    ((float4*)agg)[(size_t)node * 32 + l] =
        make_float4((a0.x + a1.x) * iv, (a0.y + a1.y) * iv,
                    (a0.z + a1.z) * iv, (a0.w + a1.w) * iv);
}

// ---- fused dual-GEMM + bias + L2-normalize + (ReLU), register-tiled -----
// Round-5 structure (inputs fully staged in 64 KB LDS, weights streamed
// from L2) + explicit weight double-buffer: prefetch k4+1's 8 weight
// float4s into a second register set before the FMA block, rotate after.
// Index wraps via &31 so the last prefetch stays in-bounds (no branch).

__global__ __launch_bounds__(256, 2) void sage_layer_kernel(const float* __restrict__ x,
                                                            const float* __restrict__ agg,
                                                            const float* __restrict__ Wl,
                                                            const float* __restrict__ bl,
                                                            const float* __restrict__ Wr,
                                                            float* __restrict__ out,
                                                            int relu, int N) {
    __shared__ float sA[BM][D];   // 32 KB
    __shared__ float sX[BM][D];   // 32 KB
    int t = threadIdx.x;
    int row0 = blockIdx.x * BM;

    {
        const float4* a4 = (const float4*)agg;
        const float4* x4 = (const float4*)x;
        float4* sA4 = (float4*)sA;
        float4* sX4 = (float4*)sX;
        for (int i = t; i < BM * (D / 4); i += 256) {
            int r = i >> 5;
            int c = i & 31;
            int gr = row0 + r;
            float4 va = make_float4(0.f, 0.f, 0.f, 0.f);
            float4 vx = va;
            if (gr < N) {
                va = a4[(size_t)gr * 32 + c];
                vx = x4[(size_t)gr * 32 + c];
            }
            sA4[i] = va;
            sX4[i] = vx;
        }
    }
    __syncthreads();

    int ct = t & 31;
    int rt = t >> 5;
    int r0 = rt * 8;

    float acc[8][4];
    {
        float4 b4 = ((const float4*)bl)[ct];
        #pragma unroll
        for (int i = 0; i < 8; ++i) {
            acc[i][0] = b4.x; acc[i][1] = b4.y; acc[i][2] = b4.z; acc[i][3] = b4.w;
        }
    }

    const float4* Wl4 = (const float4*)Wl;
    const float4* Wr4 = (const float4*)Wr;
    const float4* sA4 = (const float4*)sA;
    const float4* sX4 = (const float4*)sX;

    // prologue: load k4 = 0 weights
    float4 wl0 = Wl4[0 * 32 + ct];
    float4 wl1 = Wl4[1 * 32 + ct];
    float4 wl2 = Wl4[2 * 32 + ct];
    float4 wl3 = Wl4[3 * 32 + ct];
    float4 wr0 = Wr4[0 * 32 + ct];
    float4 wr1 = Wr4[1 * 32 + ct];
    float4 wr2 = Wr4[2 * 32 + ct];
    float4 wr3 = Wr4[3 * 32 + ct];

    for (int k4 = 0; k4 < D / 4; ++k4) {
        // prefetch next k4's weights (wraps to 0 on the last iter)
        int kn = ((k4 + 1) & 31) * 4;
        float4 nl0 = Wl4[(kn + 0) * 32 + ct];
        float4 nl1 = Wl4[(kn + 1) * 32 + ct];
        float4 nl2 = Wl4[(kn + 2) * 32 + ct];
        float4 nl3 = Wl4[(kn + 3) * 32 + ct];
        float4 nr0 = Wr4[(kn + 0) * 32 + ct];
        float4 nr1 = Wr4[(kn + 1) * 32 + ct];
        float4 nr2 = Wr4[(kn + 2) * 32 + ct];
        float4 nr3 = Wr4[(kn + 3) * 32 + ct];

        #pragma unroll
        for (int i = 0; i < 8; ++i) {
            float4 a4 = sA4[(r0 + i) * 32 + k4];
            float4 x4 = sX4[(r0 + i) * 32 + k4];
            acc[i][0] += a4.x * wl0.x + a4.y * wl1.x + a4.z * wl2.x + a4.w * wl3.x
                       + x4.x * wr0.x + x4.y * wr1.x + x4.z * wr2.x + x4.w * wr3.x;
            acc[i][1] += a4.x * wl0.y + a4.y * wl1.y + a4.z * wl2.y + a4.w * wl3.y
                       + x4.x * wr0.y + x4.y * wr1.y + x4.z * wr2.y + x4.w * wr3.y;
            acc[i][2] += a4.x * wl0.z + a4.y * wl1.z + a4.z * wl2.z + a4.w * wl3.z
                       + x4.x * wr0.z + x4.y * wr1.z + x4.z * wr2.z + x4.w * wr3.z;
            acc[i][3] += a4.x * wl0.w + a4.y * wl1.w + a4.z * wl2.w + a4.w * wl3.w
                       + x4.x * wr0.w + x4.y * wr1.w + x4.z * wr2.w + x4.w * wr3.w;
        }

        wl0 = nl0; wl1 = nl1; wl2 = nl2; wl3 = nl3;
        wr0 = nr0; wr1 = nr1; wr2 = nr2; wr3 = nr3;
    }

    float4* out4 = (float4*)out;
    #pragma unroll
    for (int i = 0; i < 8; ++i) {
        float s = acc[i][0] * acc[i][0] + acc[i][1] * acc[i][1]
                + acc[i][2] * acc[i][2] + acc[i][3] * acc[i][3];
        for (int off = 16; off; off >>= 1) s += __shfl_xor(s, off);
        float inv = 1.0f / fmaxf(sqrtf(s), 1e-12f);
        float4 o;
        o.x = acc[i][0] * inv; o.y = acc[i][1] * inv;
        o.z = acc[i][2] * inv; o.w = acc[i][3] * inv;
        if (relu) {
            o.x = fmaxf(o.x, 0.f); o.y = fmaxf(o.y, 0.f);
            o.z = fmaxf(o.z, 0.f); o.w = fmaxf(o.w, 0.f);
        }
        int gr = row0 + r0 + i;
        if (gr < N) out4[(size_t)gr * 32 + ct] = o;
    }
}

// ---- final FC + softmax: LDS-tiled, 32 rows/block, 8 threads/row --------

__global__ __launch_bounds__(256, 4) void fc_softmax_kernel(const float* __restrict__ h,
                                                            const float* __restrict__ Wfc,
                                                            const float* __restrict__ bfc,
                                                            float* __restrict__ out, int N) {
    __shared__ float sH[32 * 132];  // 16.9 KB
    __shared__ float sW[128 * 40];  // 20.5 KB
    __shared__ float sB[40];
    int t = threadIdx.x;
    int row0 = blockIdx.x * 32;

    const float4* W4 = (const float4*)Wfc;
    float4* sW4 = (float4*)sW;
    for (int i = t; i < 1280; i += 256) sW4[i] = W4[i];
    if (t < 40) sB[t] = bfc[t];

    const float4* h4 = (const float4*)h;
    for (int i = t; i < 32 * 32; i += 256) {
        int r = i >> 5, c = i & 31;
        int gr = row0 + r;
        float4 v = make_float4(0.f, 0.f, 0.f, 0.f);
        if (gr < N) v = h4[(size_t)gr * 32 + c];
        *(float4*)(sH + r * 132 + c * 4) = v;
    }
    __syncthreads();

    int r = t >> 3, sub = t & 7;
    int c0 = sub * 5;
    float acc[5];
    #pragma unroll
    for (int i = 0; i < 5; ++i) acc[i] = sB[c0 + i];

    const float* hr = sH + r * 132;
    for (int k = 0; k < 128; ++k) {
        float hv = hr[k];
        const float* wk = sW + k * 40 + c0;
        #pragma unroll
        for (int i = 0; i < 5; ++i) acc[i] += hv * wk[i];
    }

    float m = acc[0];
    #pragma unroll
    for (int i = 1; i < 5; ++i) m = fmaxf(m, acc[i]);
    for (int off = 1; off < 8; off <<= 1) m = fmaxf(m, __shfl_xor(m, off));
    float s = 0.f;
    #pragma unroll
    for (int i = 0; i < 5; ++i) { acc[i] = expf(acc[i] - m); s += acc[i]; }
    for (int off = 1; off < 8; off <<= 1) s += __shfl_xor(s, off);
    float inv = 1.0f / s;

    int gr = row0 + r;
    if (gr < N) {
        #pragma unroll
        for (int i = 0; i < 5; ++i) out[(size_t)gr * 40 + c0 + i] = acc[i] * inv;
    }
}

// ---- launcher -----------------------------------------------------------

extern "C" void kernel_launch(void* const* d_in, const int* in_sizes, int n_in,
                              void* d_out, int out_size, void* d_ws, size_t ws_size,
                              hipStream_t stream) {
    const float* x   = (const float*)d_in[0];
    const int*   e   = (const int*)d_in[1];
    const float* W1l = (const float*)d_in[2];
    const float* b1  = (const float*)d_in[3];
    const float* W1r = (const float*)d_in[4];
    const float* W2l = (const float*)d_in[5];
    const float* b2  = (const float*)d_in[6];
    const float* W2r = (const float*)d_in[7];
    const float* W3l = (const float*)d_in[8];
    const float* b3  = (const float*)d_in[9];
    const float* W3r = (const float*)d_in[10];
    const float* Wfc = (const float*)d_in[11];
    const float* bfc = (const float*)d_in[12];
    float* out = (float*)d_out;

    const int N = NN;
    const int E = in_sizes[1] / 2;

    // 16B-aligned sections
    float* h1      = (float*)d_ws;
    float* h2      = h1 + (size_t)N * D;
    float* agg     = h2 + (size_t)N * D;
    float* inv_cnt = agg + (size_t)N * D;          // N floats (N%4==0)
    int*   row_ptr = (int*)(inv_cnt + N);          // N+4 ints
    int*   cnt     = row_ptr + (N + 4);            // N ints
    int*   fill    = cnt + N;                      // N ints
    int*   bsum    = fill + N;                     // 64 ints
    int*   csr_src = bsum + 64;                    // E ints

    hipMemsetAsync(cnt, 0, sizeof(int) * N, stream);
    hipMemsetAsync(fill, 0, sizeof(int) * N, stream);

    count_kernel<<<(E + 255) / 256, 256, 0, stream>>>(e, E, cnt);
    scan_blocks_kernel<<<NB, 256, 0, stream>>>(cnt, row_ptr, bsum, N);
    scan_bsums_kernel<<<1, 64, 0, stream>>>(bsum, NB);
    scan_add_kernel<<<NB, 256, 0, stream>>>(cnt, row_ptr, bsum, inv_cnt, N, E);
    scatter_kernel<<<(E + 255) / 256, 256, 0, stream>>>(e, E, row_ptr, fill, csr_src);

    int aggBlocks = (N * 32 + 255) / 256;
    int sageBlocks = (N + BM - 1) / BM;
    int fcBlocks = (N + 31) / 32;

    aggregate_kernel<<<aggBlocks, 256, 0, stream>>>(x, row_ptr, csr_src, inv_cnt, agg, N);
    sage_layer_kernel<<<sageBlocks, 256, 0, stream>>>(x, agg, W1l, b1, W1r, h1, 1, N);

    aggregate_kernel<<<aggBlocks, 256, 0, stream>>>(h1, row_ptr, csr_src, inv_cnt, agg, N);
    sage_layer_kernel<<<sageBlocks, 256, 0, stream>>>(h1, agg, W2l, b2, W2r, h2, 1, N);

    aggregate_kernel<<<aggBlocks, 256, 0, stream>>>(h2, row_ptr, csr_src, inv_cnt, agg, N);
    sage_layer_kernel<<<sageBlocks, 256, 0, stream>>>(h2, agg, W3l, b3, W3r, h1, 0, N);

    fc_softmax_kernel<<<fcBlocks, 256, 0, stream>>>(h1, Wfc, bfc, out, N);
}